// Round 6
// baseline (535.676 us; speedup 1.0000x reference)
//
#include <hip/hip_runtime.h>
#include <hip/hip_bf16.h>

// Problem constants
#define BN 8
#define CH 256
#define NN 4096
#define QKD 32
// 1/sqrt(32) * log2(e): softmax runs in exp2 domain (M=0; logits are ~N(0,1))
constexpr float SCALE_L2E = 0.17677669529663687f * 1.4426950408889634f;
constexpr float LN_EPS = 1e-5f;

typedef float f32x4 __attribute__((ext_vector_type(4)));
typedef __bf16 bf16x8 __attribute__((ext_vector_type(8)));

// RNE float -> bf16 bit pattern
__device__ __forceinline__ unsigned short f2bf(float f) {
    union { float f; unsigned int u; } c; c.f = f;
    unsigned int r = c.u + 0x7FFFu + ((c.u >> 16) & 1u);
    return (unsigned short)(r >> 16);
}
__device__ __forceinline__ float bf2f(unsigned int u) {
    union { unsigned int u; float f; } c; c.u = u << 16; return c.f;
}

// ---------------------------------------------------------------------------
// K0: convert weights to bf16 into WB at fixed offsets.
// ---------------------------------------------------------------------------
__global__ __launch_bounds__(256) void conv_weights(
    const float* __restrict__ Wq, const float* __restrict__ Wk,
    const float* __restrict__ Wv, const float* __restrict__ W1,
    const float* __restrict__ W2, unsigned short* __restrict__ WB)
{
    const int g = blockIdx.y;
    const float* src; int n; size_t off;
    if (g == 0)      { src = Wq; n = 8192;  off = 0; }
    else if (g == 1) { src = Wk; n = 8192;  off = 8192; }
    else if (g == 2) { src = Wv; n = 65536; off = 16384; }
    else if (g == 3) { src = W1; n = 65536; off = 81920; }
    else             { src = W2; n = 65536; off = 147456; }
    int idx = (blockIdx.x * 256 + threadIdx.x) * 4;
    if (idx < n) {
        float4 v = *(const float4*)(src + idx);
        ushort4 o;
        o.x = f2bf(v.x); o.y = f2bf(v.y); o.z = f2bf(v.z); o.w = f2bf(v.w);
        *(ushort4*)(WB + off + idx) = o;
    }
}

// ---------------------------------------------------------------------------
// K1: fused x-transpose + QKV projection. grid (NN/64, BN), 256 thr.
// Staging: COALESCED fp32 row reads (4 rows x 256B per wave-instr), scalar
// b16 transpose writes into xs[n][c] (stride 266 to spread banks).
// ---------------------------------------------------------------------------
__global__ __launch_bounds__(256) void qkv_fused(
    const float* __restrict__ x, const unsigned short* __restrict__ WB,
    const float* __restrict__ bq, const float* __restrict__ bk,
    const float* __restrict__ bv,
    unsigned short* __restrict__ qB, unsigned short* __restrict__ kT,
    unsigned short* __restrict__ vB)
{
    const int nt = blockIdx.x, b = blockIdx.y;
    const int tid = threadIdx.x;
    const int w = tid >> 6, lane = tid & 63, qd = lane >> 4, lm = lane & 15;
    const int n0 = nt * 64;

    __shared__ unsigned short xs[64][266];

    {   // stage: per iter 256 thr x float4 = 16 c-rows of 64 n, coalesced
        const float* xb = x + (size_t)b * CH * NN + n0;
        const int cr = tid >> 4, n4 = (tid & 15) * 4;
        for (int it = 0; it < 16; ++it) {
            int c = it * 16 + cr;
            float4 v = *(const float4*)(xb + (size_t)c * NN + n4);
            xs[n4 + 0][c] = f2bf(v.x);
            xs[n4 + 1][c] = f2bf(v.y);
            xs[n4 + 2][c] = f2bf(v.z);
            xs[n4 + 3][c] = f2bf(v.w);
        }
    }
    __syncthreads();

    const unsigned short* WqB = WB;
    const unsigned short* WkB = WB + 8192;
    const unsigned short* WvB = WB + 16384;

    f32x4 accv[4][4];
    f32x4 acck[4];
    for (int cs = 0; cs < 4; ++cs)
        for (int t = 0; t < 4; ++t) accv[cs][t] = (f32x4){0.f, 0.f, 0.f, 0.f};
    for (int t = 0; t < 4; ++t) acck[t] = (f32x4){0.f, 0.f, 0.f, 0.f};

    const unsigned short* wv_row = WvB + (size_t)(64 * w + lm) * CH;
    const unsigned short* wk_row = (w < 2)
        ? WkB + (size_t)(16 * w + lm) * CH
        : WqB + (size_t)(16 * (w - 2) + lm) * CH;

    for (int kk = 0; kk < 8; ++kk) {
        bf16x8 bf[4];
        for (int t = 0; t < 4; ++t)
            bf[t] = *(const bf16x8*)&xs[16 * t + lm][32 * kk + 8 * qd];
        bf16x8 ak = *(const bf16x8*)(wk_row + 32 * kk + 8 * qd);
        for (int t = 0; t < 4; ++t)
            acck[t] = __builtin_amdgcn_mfma_f32_16x16x32_bf16(ak, bf[t], acck[t], 0, 0, 0);
        for (int cs = 0; cs < 4; ++cs) {
            bf16x8 av = *(const bf16x8*)(wv_row + (size_t)(16 * cs) * CH + 32 * kk + 8 * qd);
            for (int t = 0; t < 4; ++t)
                accv[cs][t] = __builtin_amdgcn_mfma_f32_16x16x32_bf16(av, bf[t], accv[cs][t], 0, 0, 0);
        }
    }

    for (int cs = 0; cs < 4; ++cs) {
        int c0 = 64 * w + 16 * cs + 4 * qd;
        float4 bb = *(const float4*)&bv[c0];
        unsigned short* vbb = vB + ((size_t)b * CH + c0) * NN;
        for (int t = 0; t < 4; ++t) {
            int m = n0 + 16 * t + lm;
            vbb[0 * NN + m] = f2bf(accv[cs][t].x + bb.x);
            vbb[1 * NN + m] = f2bf(accv[cs][t].y + bb.y);
            vbb[2 * NN + m] = f2bf(accv[cs][t].z + bb.z);
            vbb[3 * NN + m] = f2bf(accv[cs][t].w + bb.w);
        }
    }
    if (w < 2) {
        int o0 = 16 * w + 4 * qd;
        float4 bb = *(const float4*)&bk[o0];
        unsigned short* kbb = kT + (size_t)b * NN * QKD;
        for (int t = 0; t < 4; ++t) {
            size_t m = n0 + 16 * t + lm;
            kbb[m * QKD + o0 + 0] = f2bf(acck[t].x + bb.x);
            kbb[m * QKD + o0 + 1] = f2bf(acck[t].y + bb.y);
            kbb[m * QKD + o0 + 2] = f2bf(acck[t].z + bb.z);
            kbb[m * QKD + o0 + 3] = f2bf(acck[t].w + bb.w);
        }
    } else {
        int o0 = 16 * (w - 2) + 4 * qd;
        float4 bb = *(const float4*)&bq[o0];
        unsigned short* qbb = qB + (size_t)b * NN * QKD;
        for (int t = 0; t < 4; ++t) {
            size_t m = n0 + 16 * t + lm;
            qbb[m * QKD + o0 + 0] = f2bf((acck[t].x + bb.x) * SCALE_L2E);
            qbb[m * QKD + o0 + 1] = f2bf((acck[t].y + bb.y) * SCALE_L2E);
            qbb[m * QKD + o0 + 2] = f2bf((acck[t].z + bb.z) * SCALE_L2E);
            qbb[m * QKD + o0 + 3] = f2bf((acck[t].w + bb.w) * SCALE_L2E);
        }
    }
}

// ---------------------------------------------------------------------------
// K2: per-key-column softmax denom: rD[n] = 1 / sum_m exp2(l[m,n]) (M=0).
// grid (NN/128, BN), 256 thr.
// ---------------------------------------------------------------------------
__global__ __launch_bounds__(256) void colstats(
    const unsigned short* __restrict__ qB, const unsigned short* __restrict__ kT,
    float* __restrict__ rD)
{
    const int nt = blockIdx.x, b = blockIdx.y;
    const int tid = threadIdx.x;
    const int w = tid >> 6, lane = tid & 63, qd = lane >> 4, lm = lane & 15;
    const int n0 = nt * 128;

    const unsigned short* qbb = qB + (size_t)b * NN * QKD;
    const unsigned short* kbb = kT + (size_t)b * NN * QKD;
    bf16x8 ka0 = *(const bf16x8*)(kbb + (size_t)(n0 + 16 * w + lm) * QKD + 8 * qd);
    bf16x8 ka1 = *(const bf16x8*)(kbb + (size_t)(n0 + 64 + 16 * w + lm) * QKD + 8 * qd);

    float runS[2][4];
    for (int h = 0; h < 2; ++h)
        for (int r = 0; r < 4; ++r) runS[h][r] = 0.f;

    for (int m0 = 0; m0 < NN; m0 += 64) {
        f32x4 zero = {0.f, 0.f, 0.f, 0.f};
        f32x4 sf0[4], sf1[4];
        for (int t = 0; t < 4; ++t) {
            bf16x8 qf = *(const bf16x8*)(qbb + (size_t)(m0 + 16 * t + lm) * QKD + 8 * qd);
            sf0[t] = __builtin_amdgcn_mfma_f32_16x16x32_bf16(ka0, qf, zero, 0, 0, 0);
            sf1[t] = __builtin_amdgcn_mfma_f32_16x16x32_bf16(ka1, qf, zero, 0, 0, 0);
        }
        for (int t = 0; t < 4; ++t)
            for (int r = 0; r < 4; ++r) {
                runS[0][r] += exp2f(sf0[t][r]);
                runS[1][r] += exp2f(sf1[t][r]);
            }
    }

    for (int h = 0; h < 2; ++h)
        for (int r = 0; r < 4; ++r) {
            float S = runS[h][r];
            for (int mask = 1; mask < 16; mask <<= 1)
                S += __shfl_xor(S, mask, 64);
            if (lm == 0)
                rD[(size_t)b * NN + n0 + 64 * h + 16 * w + 4 * qd + r] = 1.0f / S;
        }
}

// ---------------------------------------------------------------------------
// K3: fused attention + MLP + LN-sums. grid (NN/64, BN), 512 thr = 8 waves.
// LDS 34.9 KB (MLP runs in two 32-m halves inside the psT union) -> 4 blk/CU.
// Wave w: attention c-slice 32w..+31; S rows 16w..+15 per 128-n chunk,
// p = exp2(l)*rD[n]. Double-buffered psT, 1 barrier/chunk.
// ---------------------------------------------------------------------------
__global__ __launch_bounds__(512, 8) void attn_mlp(
    const unsigned short* __restrict__ qB, const unsigned short* __restrict__ kT,
    const unsigned short* __restrict__ vB, const float* __restrict__ rD,
    const unsigned short* __restrict__ W1B, const float* __restrict__ b1,
    const unsigned short* __restrict__ W2B, const float* __restrict__ b2,
    unsigned short* __restrict__ yB, float* __restrict__ sums)
{
    const int mt = blockIdx.x, b = blockIdx.y;
    const int tid = threadIdx.x;
    const int w = tid >> 6, lane = tid & 63, qd = lane >> 4, lm = lane & 15;
    const int m0 = mt * 64;
    constexpr int NC = NN / 128;  // 32 chunks

    __shared__ union SMem {
        unsigned short psT[2][64][136];                                   // 34816 B
        struct { unsigned short oT[32][264]; unsigned short hT[32][264]; } mlp;  // 33792 B
    } sm;
    __shared__ float rs1[8], rs2[8];

    bf16x8 qfrag[4];
    for (int t = 0; t < 4; ++t)
        qfrag[t] = *(const bf16x8*)(qB + ((size_t)b * NN + m0 + 16 * t + lm) * QKD + 8 * qd);

    f32x4 facc[2][4];  // [cs][t]
    for (int cs = 0; cs < 2; ++cs)
        for (int t = 0; t < 4; ++t) facc[cs][t] = (f32x4){0.f, 0.f, 0.f, 0.f};

    const unsigned short* kbb = kT + (size_t)b * NN * QKD;
    const unsigned short* vbb = vB + ((size_t)b * CH + 32 * w) * NN;
    const float* Rb = rD + (size_t)b * NN;

    // prologue: S for chunk 0 -> psT[0]; prefetch ka for chunk 1
    bf16x8 ka_next;
    {
        bf16x8 ka = *(const bf16x8*)(kbb + (size_t)(16 * w + lm) * QKD + 8 * qd);
        ka_next   = *(const bf16x8*)(kbb + (size_t)(128 + 16 * w + lm) * QKD + 8 * qd);
        float4 Rv = *(const float4*)(Rb + 16 * w + 4 * qd);
        f32x4 z = {0.f, 0.f, 0.f, 0.f};
        for (int t = 0; t < 4; ++t) {
            f32x4 sf = __builtin_amdgcn_mfma_f32_16x16x32_bf16(ka, qfrag[t], z, 0, 0, 0);
            ushort4 pk;
            pk.x = f2bf(exp2f(sf.x) * Rv.x); pk.y = f2bf(exp2f(sf.y) * Rv.y);
            pk.z = f2bf(exp2f(sf.z) * Rv.z); pk.w = f2bf(exp2f(sf.w) * Rv.w);
            *(ushort4*)&sm.psT[0][16 * t + lm][16 * w + 4 * qd] = pk;
        }
    }

    for (int ic = 0; ic < NC; ++ic) {
        __syncthreads();
        const int cur = ic & 1;
        if (ic + 1 < NC) {  // S phase for chunk ic+1 into the other buffer
            f32x4 z = {0.f, 0.f, 0.f, 0.f};
            f32x4 sf[4];
            for (int t = 0; t < 4; ++t)
                sf[t] = __builtin_amdgcn_mfma_f32_16x16x32_bf16(ka_next, qfrag[t], z, 0, 0, 0);
            if (ic + 2 < NC)
                ka_next = *(const bf16x8*)(kbb + (size_t)(128 * (ic + 2) + 16 * w + lm) * QKD + 8 * qd);
            float4 Rv = *(const float4*)(Rb + 128 * (ic + 1) + 16 * w + 4 * qd);
            for (int t = 0; t < 4; ++t) {
                ushort4 pk;
                pk.x = f2bf(exp2f(sf[t].x) * Rv.x); pk.y = f2bf(exp2f(sf[t].y) * Rv.y);
                pk.z = f2bf(exp2f(sf[t].z) * Rv.z); pk.w = f2bf(exp2f(sf[t].w) * Rv.w);
                *(ushort4*)&sm.psT[cur ^ 1][16 * t + lm][16 * w + 4 * qd] = pk;
            }
        }
        // PV phase for chunk ic: 128 n, c-slice 32w..+31
        const unsigned short* vcc = vbb + 128 * ic;
        for (int s2 = 0; s2 < 4; ++s2) {
            bf16x8 pb[4];
            for (int t = 0; t < 4; ++t)
                pb[t] = *(const bf16x8*)&sm.psT[cur][16 * t + lm][32 * s2 + 8 * qd];
            for (int cs = 0; cs < 2; ++cs) {
                bf16x8 va = *(const bf16x8*)(vcc + (size_t)(16 * cs + lm) * NN + 32 * s2 + 8 * qd);
                for (int t = 0; t < 4; ++t)
                    facc[cs][t] = __builtin_amdgcn_mfma_f32_16x16x32_bf16(va, pb[t], facc[cs][t], 0, 0, 0);
            }
        }
    }

    __syncthreads();  // psT fully consumed; mlp struct may alias

    float s1 = 0.f, s2v = 0.f;
    for (int half = 0; half < 2; ++half) {
        // O half-tile -> oT[m-local 32][c 256]
        for (int cs = 0; cs < 2; ++cs)
            for (int tt = 0; tt < 2; ++tt) {
                const f32x4 fa = facc[cs][2 * half + tt];
                ushort4 pk;
                pk.x = f2bf(fa.x); pk.y = f2bf(fa.y);
                pk.z = f2bf(fa.z); pk.w = f2bf(fa.w);
                *(ushort4*)&sm.mlp.oT[16 * tt + lm][32 * w + 16 * cs + 4 * qd] = pk;
            }
        __syncthreads();

        // MLP phase 1: h = relu(W1 @ O + b1); wave w -> j rows 32w..32w+31
        f32x4 a1[2][2];
        for (int js = 0; js < 2; ++js)
            for (int tt = 0; tt < 2; ++tt) a1[js][tt] = (f32x4){0.f, 0.f, 0.f, 0.f};
        for (int kk = 0; kk < 8; ++kk) {
            bf16x8 bf[2];
            for (int tt = 0; tt < 2; ++tt)
                bf[tt] = *(const bf16x8*)&sm.mlp.oT[16 * tt + lm][32 * kk + 8 * qd];
            for (int js = 0; js < 2; ++js) {
                bf16x8 a = *(const bf16x8*)(W1B + (size_t)(32 * w + 16 * js + lm) * CH + 32 * kk + 8 * qd);
                for (int tt = 0; tt < 2; ++tt)
                    a1[js][tt] = __builtin_amdgcn_mfma_f32_16x16x32_bf16(a, bf[tt], a1[js][tt], 0, 0, 0);
            }
        }
        for (int js = 0; js < 2; ++js) {
            int j0 = 32 * w + 16 * js + 4 * qd;
            float4 bb = *(const float4*)&b1[j0];
            for (int tt = 0; tt < 2; ++tt) {
                ushort4 pk;
                pk.x = f2bf(fmaxf(a1[js][tt].x + bb.x, 0.f));
                pk.y = f2bf(fmaxf(a1[js][tt].y + bb.y, 0.f));
                pk.z = f2bf(fmaxf(a1[js][tt].z + bb.z, 0.f));
                pk.w = f2bf(fmaxf(a1[js][tt].w + bb.w, 0.f));
                *(ushort4*)&sm.mlp.hT[16 * tt + lm][j0] = pk;
            }
        }
        __syncthreads();

        // MLP phase 2: y = W2 @ h + b2; wave w -> c rows 32w..32w+31
        f32x4 a2[2][2];
        for (int cs = 0; cs < 2; ++cs)
            for (int tt = 0; tt < 2; ++tt) a2[cs][tt] = (f32x4){0.f, 0.f, 0.f, 0.f};
        for (int kk = 0; kk < 8; ++kk) {
            bf16x8 hb[2];
            for (int tt = 0; tt < 2; ++tt)
                hb[tt] = *(const bf16x8*)&sm.mlp.hT[16 * tt + lm][32 * kk + 8 * qd];
            for (int cs = 0; cs < 2; ++cs) {
                bf16x8 a = *(const bf16x8*)(W2B + (size_t)(32 * w + 16 * cs + lm) * CH + 32 * kk + 8 * qd);
                for (int tt = 0; tt < 2; ++tt)
                    a2[cs][tt] = __builtin_amdgcn_mfma_f32_16x16x32_bf16(a, hb[tt], a2[cs][tt], 0, 0, 0);
            }
        }
        for (int cs = 0; cs < 2; ++cs) {
            int c0 = 32 * w + 16 * cs + 4 * qd;
            float4 bb = *(const float4*)&b2[c0];
            unsigned short* ybb = yB + ((size_t)b * CH + c0) * NN + m0;
            for (int tt = 0; tt < 2; ++tt) {
                int m = 32 * half + 16 * tt + lm;
                float v0 = a2[cs][tt].x + bb.x, v1 = a2[cs][tt].y + bb.y;
                float v2 = a2[cs][tt].z + bb.z, v3 = a2[cs][tt].w + bb.w;
                s1 += v0 + v1 + v2 + v3;
                s2v += v0 * v0 + v1 * v1 + v2 * v2 + v3 * v3;
                ybb[0 * NN + m] = f2bf(v0);
                ybb[1 * NN + m] = f2bf(v1);
                ybb[2 * NN + m] = f2bf(v2);
                ybb[3 * NN + m] = f2bf(v3);
            }
        }
    }

    for (int off = 32; off > 0; off >>= 1) {
        s1  += __shfl_down(s1, off, 64);
        s2v += __shfl_down(s2v, off, 64);
    }
    if (lane == 0) { rs1[w] = s1; rs2[w] = s2v; }
    __syncthreads();
    if (tid == 0) {
        float t1 = 0.f, t2 = 0.f;
        for (int i = 0; i < 8; ++i) { t1 += rs1[i]; t2 += rs2[i]; }
        atomicAdd(&sums[b], t1);
        atomicAdd(&sums[BN + b], t2);
    }
}

// ---------------------------------------------------------------------------
// K5: LayerNorm scale from bf16 y
// ---------------------------------------------------------------------------
__global__ __launch_bounds__(256) void ln_final(
    const unsigned short* __restrict__ yB, const float* __restrict__ sums,
    const float* __restrict__ gamma, const float* __restrict__ beta,
    float* __restrict__ out)
{
    const size_t i8 = ((size_t)blockIdx.x * 256 + threadIdx.x) * 8;
    const int b = (int)(i8 >> 20);
    const size_t r = i8 & ((size_t)CH * NN - 1);
    const float inv_n = 1.0f / ((float)CH * (float)NN);
    float mu = sums[b] * inv_n;
    float var = sums[BN + b] * inv_n - mu * mu;
    float inv = rsqrtf(var + LN_EPS);
    uint4 u = *(const uint4*)(yB + i8);
    float y[8];
    y[0] = bf2f(u.x & 0xFFFFu); y[1] = bf2f(u.x >> 16);
    y[2] = bf2f(u.y & 0xFFFFu); y[3] = bf2f(u.y >> 16);
    y[4] = bf2f(u.z & 0xFFFFu); y[5] = bf2f(u.z >> 16);
    y[6] = bf2f(u.w & 0xFFFFu); y[7] = bf2f(u.w >> 16);
    float4 g0 = *(const float4*)(gamma + r);
    float4 g1 = *(const float4*)(gamma + r + 4);
    float4 be0 = *(const float4*)(beta + r);
    float4 be1 = *(const float4*)(beta + r + 4);
    float4 o0, o1;
    o0.x = (y[0] - mu) * inv * g0.x + be0.x;
    o0.y = (y[1] - mu) * inv * g0.y + be0.y;
    o0.z = (y[2] - mu) * inv * g0.z + be0.z;
    o0.w = (y[3] - mu) * inv * g0.w + be0.w;
    o1.x = (y[4] - mu) * inv * g1.x + be1.x;
    o1.y = (y[5] - mu) * inv * g1.y + be1.y;
    o1.z = (y[6] - mu) * inv * g1.z + be1.z;
    o1.w = (y[7] - mu) * inv * g1.w + be1.w;
    *(float4*)(out + i8) = o0;
    *(float4*)(out + i8 + 4) = o1;
}

// ---------------------------------------------------------------------------
extern "C" void kernel_launch(void* const* d_in, const int* in_sizes, int n_in,
                              void* d_out, int out_size, void* d_ws, size_t ws_size,
                              hipStream_t stream)
{
    const float* x     = (const float*)d_in[0];
    const float* Wq    = (const float*)d_in[1];
    const float* bq    = (const float*)d_in[2];
    const float* Wk    = (const float*)d_in[3];
    const float* bk    = (const float*)d_in[4];
    const float* Wv    = (const float*)d_in[5];
    const float* bv    = (const float*)d_in[6];
    const float* W1    = (const float*)d_in[7];
    const float* b1    = (const float*)d_in[8];
    const float* W2    = (const float*)d_in[9];
    const float* b2    = (const float*)d_in[10];
    const float* gamma = (const float*)d_in[11];
    const float* beta  = (const float*)d_in[12];
    float* out = (float*)d_out;

    // workspace layout (~37 MB)
    unsigned short* qB  = (unsigned short*)d_ws;                   // 2 MB
    unsigned short* kTb = qB  + (size_t)BN * NN * QKD;             // 2 MB
    unsigned short* vB  = kTb + (size_t)BN * NN * QKD;             // 16 MB
    unsigned short* yB  = vB  + (size_t)BN * CH * NN;              // 16 MB
    unsigned short* WB  = yB  + (size_t)BN * CH * NN;              // 416 KB
    float* rD   = (float*)(WB + 212992);                           // 128 KB
    float* sums = rD + (size_t)BN * NN;                            // 64 B

    hipMemsetAsync(sums, 0, 2 * BN * sizeof(float), stream);

    conv_weights<<<dim3(64, 5), 256, 0, stream>>>(Wq, Wk, Wv, W1, W2, WB);
    qkv_fused<<<dim3(NN / 64, BN), 256, 0, stream>>>(x, WB, bq, bk, bv,
                                                     qB, kTb, vB);
    colstats<<<dim3(NN / 128, BN), 256, 0, stream>>>(qB, kTb, rD);
    attn_mlp<<<dim3(NN / 64, BN), 512, 0, stream>>>(qB, kTb, vB, rD,
                                                    WB + 81920, b1,
                                                    WB + 147456, b2, yB, sums);
    ln_final<<<dim3((BN * CH * NN) / 2048), 256, 0, stream>>>(yB, sums, gamma,
                                                              beta, out);
}

// Round 7
// 349.961 us; speedup vs baseline: 1.5307x; 1.5307x over previous
//
#include <hip/hip_runtime.h>
#include <hip/hip_bf16.h>

// Problem constants
#define BN 8
#define CH 256
#define NN 4096
#define QKD 32
// 1/sqrt(32) * log2(e): softmax runs in exp2 domain (M=0; logits are ~N(0,1))
constexpr float SCALE_L2E = 0.17677669529663687f * 1.4426950408889634f;
constexpr float LN_EPS = 1e-5f;

typedef float f32x4 __attribute__((ext_vector_type(4)));
typedef __bf16 bf16x8 __attribute__((ext_vector_type(8)));

// RNE float -> bf16 bit pattern
__device__ __forceinline__ unsigned short f2bf(float f) {
    union { float f; unsigned int u; } c; c.f = f;
    unsigned int r = c.u + 0x7FFFu + ((c.u >> 16) & 1u);
    return (unsigned short)(r >> 16);
}
__device__ __forceinline__ float bf2f(unsigned int u) {
    union { unsigned int u; float f; } c; c.u = u << 16; return c.f;
}

// ---------------------------------------------------------------------------
// K0: convert weights to bf16 into WB at fixed offsets.
// ---------------------------------------------------------------------------
__global__ __launch_bounds__(256) void conv_weights(
    const float* __restrict__ Wq, const float* __restrict__ Wk,
    const float* __restrict__ Wv, const float* __restrict__ W1,
    const float* __restrict__ W2, unsigned short* __restrict__ WB)
{
    const int g = blockIdx.y;
    const float* src; int n; size_t off;
    if (g == 0)      { src = Wq; n = 8192;  off = 0; }
    else if (g == 1) { src = Wk; n = 8192;  off = 8192; }
    else if (g == 2) { src = Wv; n = 65536; off = 16384; }
    else if (g == 3) { src = W1; n = 65536; off = 81920; }
    else             { src = W2; n = 65536; off = 147456; }
    int idx = (blockIdx.x * 256 + threadIdx.x) * 4;
    if (idx < n) {
        float4 v = *(const float4*)(src + idx);
        ushort4 o;
        o.x = f2bf(v.x); o.y = f2bf(v.y); o.z = f2bf(v.z); o.w = f2bf(v.w);
        *(ushort4*)(WB + off + idx) = o;
    }
}

// ---------------------------------------------------------------------------
// K1: fused x-transpose + QKV projection. grid (NN/64, BN), 256 thr.
// Staging: COALESCED fp32 row reads (4 rows x 256B per wave-instr), scalar
// b16 transpose writes into xs[n][c] (stride 266 to spread banks).
// ---------------------------------------------------------------------------
__global__ __launch_bounds__(256) void qkv_fused(
    const float* __restrict__ x, const unsigned short* __restrict__ WB,
    const float* __restrict__ bq, const float* __restrict__ bk,
    const float* __restrict__ bv,
    unsigned short* __restrict__ qB, unsigned short* __restrict__ kT,
    unsigned short* __restrict__ vB)
{
    const int nt = blockIdx.x, b = blockIdx.y;
    const int tid = threadIdx.x;
    const int w = tid >> 6, lane = tid & 63, qd = lane >> 4, lm = lane & 15;
    const int n0 = nt * 64;

    __shared__ unsigned short xs[64][266];

    {   // stage: per iter 256 thr x float4 = 16 c-rows of 64 n, coalesced
        const float* xb = x + (size_t)b * CH * NN + n0;
        const int cr = tid >> 4, n4 = (tid & 15) * 4;
        for (int it = 0; it < 16; ++it) {
            int c = it * 16 + cr;
            float4 v = *(const float4*)(xb + (size_t)c * NN + n4);
            xs[n4 + 0][c] = f2bf(v.x);
            xs[n4 + 1][c] = f2bf(v.y);
            xs[n4 + 2][c] = f2bf(v.z);
            xs[n4 + 3][c] = f2bf(v.w);
        }
    }
    __syncthreads();

    const unsigned short* WqB = WB;
    const unsigned short* WkB = WB + 8192;
    const unsigned short* WvB = WB + 16384;

    f32x4 accv[4][4];
    f32x4 acck[4];
    for (int cs = 0; cs < 4; ++cs)
        for (int t = 0; t < 4; ++t) accv[cs][t] = (f32x4){0.f, 0.f, 0.f, 0.f};
    for (int t = 0; t < 4; ++t) acck[t] = (f32x4){0.f, 0.f, 0.f, 0.f};

    const unsigned short* wv_row = WvB + (size_t)(64 * w + lm) * CH;
    const unsigned short* wk_row = (w < 2)
        ? WkB + (size_t)(16 * w + lm) * CH
        : WqB + (size_t)(16 * (w - 2) + lm) * CH;

    for (int kk = 0; kk < 8; ++kk) {
        bf16x8 bf[4];
        for (int t = 0; t < 4; ++t)
            bf[t] = *(const bf16x8*)&xs[16 * t + lm][32 * kk + 8 * qd];
        bf16x8 ak = *(const bf16x8*)(wk_row + 32 * kk + 8 * qd);
        for (int t = 0; t < 4; ++t)
            acck[t] = __builtin_amdgcn_mfma_f32_16x16x32_bf16(ak, bf[t], acck[t], 0, 0, 0);
        for (int cs = 0; cs < 4; ++cs) {
            bf16x8 av = *(const bf16x8*)(wv_row + (size_t)(16 * cs) * CH + 32 * kk + 8 * qd);
            for (int t = 0; t < 4; ++t)
                accv[cs][t] = __builtin_amdgcn_mfma_f32_16x16x32_bf16(av, bf[t], accv[cs][t], 0, 0, 0);
        }
    }

    for (int cs = 0; cs < 4; ++cs) {
        int c0 = 64 * w + 16 * cs + 4 * qd;
        float4 bb = *(const float4*)&bv[c0];
        unsigned short* vbb = vB + ((size_t)b * CH + c0) * NN;
        for (int t = 0; t < 4; ++t) {
            int m = n0 + 16 * t + lm;
            vbb[0 * NN + m] = f2bf(accv[cs][t].x + bb.x);
            vbb[1 * NN + m] = f2bf(accv[cs][t].y + bb.y);
            vbb[2 * NN + m] = f2bf(accv[cs][t].z + bb.z);
            vbb[3 * NN + m] = f2bf(accv[cs][t].w + bb.w);
        }
    }
    if (w < 2) {
        int o0 = 16 * w + 4 * qd;
        float4 bb = *(const float4*)&bk[o0];
        unsigned short* kbb = kT + (size_t)b * NN * QKD;
        for (int t = 0; t < 4; ++t) {
            size_t m = n0 + 16 * t + lm;
            kbb[m * QKD + o0 + 0] = f2bf(acck[t].x + bb.x);
            kbb[m * QKD + o0 + 1] = f2bf(acck[t].y + bb.y);
            kbb[m * QKD + o0 + 2] = f2bf(acck[t].z + bb.z);
            kbb[m * QKD + o0 + 3] = f2bf(acck[t].w + bb.w);
        }
    } else {
        int o0 = 16 * (w - 2) + 4 * qd;
        float4 bb = *(const float4*)&bq[o0];
        unsigned short* qbb = qB + (size_t)b * NN * QKD;
        for (int t = 0; t < 4; ++t) {
            size_t m = n0 + 16 * t + lm;
            qbb[m * QKD + o0 + 0] = f2bf((acck[t].x + bb.x) * SCALE_L2E);
            qbb[m * QKD + o0 + 1] = f2bf((acck[t].y + bb.y) * SCALE_L2E);
            qbb[m * QKD + o0 + 2] = f2bf((acck[t].z + bb.z) * SCALE_L2E);
            qbb[m * QKD + o0 + 3] = f2bf((acck[t].w + bb.w) * SCALE_L2E);
        }
    }
}

// ---------------------------------------------------------------------------
// K2: per-key-column softmax denom: rD[n] = 1 / sum_m exp2(l[m,n]) (M=0).
// grid (NN/128, BN), 256 thr.
// ---------------------------------------------------------------------------
__global__ __launch_bounds__(256) void colstats(
    const unsigned short* __restrict__ qB, const unsigned short* __restrict__ kT,
    float* __restrict__ rD)
{
    const int nt = blockIdx.x, b = blockIdx.y;
    const int tid = threadIdx.x;
    const int w = tid >> 6, lane = tid & 63, qd = lane >> 4, lm = lane & 15;
    const int n0 = nt * 128;

    const unsigned short* qbb = qB + (size_t)b * NN * QKD;
    const unsigned short* kbb = kT + (size_t)b * NN * QKD;
    bf16x8 ka0 = *(const bf16x8*)(kbb + (size_t)(n0 + 16 * w + lm) * QKD + 8 * qd);
    bf16x8 ka1 = *(const bf16x8*)(kbb + (size_t)(n0 + 64 + 16 * w + lm) * QKD + 8 * qd);

    float runS[2][4];
    for (int h = 0; h < 2; ++h)
        for (int r = 0; r < 4; ++r) runS[h][r] = 0.f;

    for (int m0 = 0; m0 < NN; m0 += 64) {
        f32x4 zero = {0.f, 0.f, 0.f, 0.f};
        f32x4 sf0[4], sf1[4];
        for (int t = 0; t < 4; ++t) {
            bf16x8 qf = *(const bf16x8*)(qbb + (size_t)(m0 + 16 * t + lm) * QKD + 8 * qd);
            sf0[t] = __builtin_amdgcn_mfma_f32_16x16x32_bf16(ka0, qf, zero, 0, 0, 0);
            sf1[t] = __builtin_amdgcn_mfma_f32_16x16x32_bf16(ka1, qf, zero, 0, 0, 0);
        }
        for (int t = 0; t < 4; ++t)
            for (int r = 0; r < 4; ++r) {
                runS[0][r] += exp2f(sf0[t][r]);
                runS[1][r] += exp2f(sf1[t][r]);
            }
    }

    for (int h = 0; h < 2; ++h)
        for (int r = 0; r < 4; ++r) {
            float S = runS[h][r];
            for (int mask = 1; mask < 16; mask <<= 1)
                S += __shfl_xor(S, mask, 64);
            if (lm == 0)
                rD[(size_t)b * NN + n0 + 64 * h + 16 * w + 4 * qd + r] = 1.0f / S;
        }
}

// ---------------------------------------------------------------------------
// K3: fused attention + MLP + LN-sums. grid (NN/64, BN), 512 thr = 8 waves.
// LDS 34.9 KB (MLP runs in two 32-m halves inside the psT union); with the
// natural 64-VGPR allocation this runs 4 blk/CU (32 waves).
// NOTE: launch_bounds min-waves MUST stay 4: demanding 8 forces a 32-VGPR
// allocation -> scratch spill -> 1 GB/dispatch HBM traffic (round-6 lesson).
// Wave w: attention c-slice 32w..+31; S rows 16w..+15 per 128-n chunk,
// p = exp2(l)*rD[n]. Double-buffered psT, 1 barrier/chunk.
// ---------------------------------------------------------------------------
__global__ __launch_bounds__(512, 4) void attn_mlp(
    const unsigned short* __restrict__ qB, const unsigned short* __restrict__ kT,
    const unsigned short* __restrict__ vB, const float* __restrict__ rD,
    const unsigned short* __restrict__ W1B, const float* __restrict__ b1,
    const unsigned short* __restrict__ W2B, const float* __restrict__ b2,
    unsigned short* __restrict__ yB, float* __restrict__ sums)
{
    const int mt = blockIdx.x, b = blockIdx.y;
    const int tid = threadIdx.x;
    const int w = tid >> 6, lane = tid & 63, qd = lane >> 4, lm = lane & 15;
    const int m0 = mt * 64;
    constexpr int NC = NN / 128;  // 32 chunks

    __shared__ union SMem {
        unsigned short psT[2][64][136];                                   // 34816 B
        struct { unsigned short oT[32][264]; unsigned short hT[32][264]; } mlp;  // 33792 B
    } sm;
    __shared__ float rs1[8], rs2[8];

    bf16x8 qfrag[4];
    for (int t = 0; t < 4; ++t)
        qfrag[t] = *(const bf16x8*)(qB + ((size_t)b * NN + m0 + 16 * t + lm) * QKD + 8 * qd);

    f32x4 facc[2][4];  // [cs][t]
    for (int cs = 0; cs < 2; ++cs)
        for (int t = 0; t < 4; ++t) facc[cs][t] = (f32x4){0.f, 0.f, 0.f, 0.f};

    const unsigned short* kbb = kT + (size_t)b * NN * QKD;
    const unsigned short* vbb = vB + ((size_t)b * CH + 32 * w) * NN;
    const float* Rb = rD + (size_t)b * NN;

    // prologue: S for chunk 0 -> psT[0]; prefetch ka for chunk 1
    bf16x8 ka_next;
    {
        bf16x8 ka = *(const bf16x8*)(kbb + (size_t)(16 * w + lm) * QKD + 8 * qd);
        ka_next   = *(const bf16x8*)(kbb + (size_t)(128 + 16 * w + lm) * QKD + 8 * qd);
        float4 Rv = *(const float4*)(Rb + 16 * w + 4 * qd);
        f32x4 z = {0.f, 0.f, 0.f, 0.f};
        for (int t = 0; t < 4; ++t) {
            f32x4 sf = __builtin_amdgcn_mfma_f32_16x16x32_bf16(ka, qfrag[t], z, 0, 0, 0);
            ushort4 pk;
            pk.x = f2bf(exp2f(sf.x) * Rv.x); pk.y = f2bf(exp2f(sf.y) * Rv.y);
            pk.z = f2bf(exp2f(sf.z) * Rv.z); pk.w = f2bf(exp2f(sf.w) * Rv.w);
            *(ushort4*)&sm.psT[0][16 * t + lm][16 * w + 4 * qd] = pk;
        }
    }

    for (int ic = 0; ic < NC; ++ic) {
        __syncthreads();
        const int cur = ic & 1;
        if (ic + 1 < NC) {  // S phase for chunk ic+1 into the other buffer
            f32x4 z = {0.f, 0.f, 0.f, 0.f};
            f32x4 sf[4];
            for (int t = 0; t < 4; ++t)
                sf[t] = __builtin_amdgcn_mfma_f32_16x16x32_bf16(ka_next, qfrag[t], z, 0, 0, 0);
            if (ic + 2 < NC)
                ka_next = *(const bf16x8*)(kbb + (size_t)(128 * (ic + 2) + 16 * w + lm) * QKD + 8 * qd);
            float4 Rv = *(const float4*)(Rb + 128 * (ic + 1) + 16 * w + 4 * qd);
            for (int t = 0; t < 4; ++t) {
                ushort4 pk;
                pk.x = f2bf(exp2f(sf[t].x) * Rv.x); pk.y = f2bf(exp2f(sf[t].y) * Rv.y);
                pk.z = f2bf(exp2f(sf[t].z) * Rv.z); pk.w = f2bf(exp2f(sf[t].w) * Rv.w);
                *(ushort4*)&sm.psT[cur ^ 1][16 * t + lm][16 * w + 4 * qd] = pk;
            }
        }
        // PV phase for chunk ic: 128 n, c-slice 32w..+31
        const unsigned short* vcc = vbb + 128 * ic;
        for (int s2 = 0; s2 < 4; ++s2) {
            bf16x8 pb[4];
            for (int t = 0; t < 4; ++t)
                pb[t] = *(const bf16x8*)&sm.psT[cur][16 * t + lm][32 * s2 + 8 * qd];
            for (int cs = 0; cs < 2; ++cs) {
                bf16x8 va = *(const bf16x8*)(vcc + (size_t)(16 * cs + lm) * NN + 32 * s2 + 8 * qd);
                for (int t = 0; t < 4; ++t)
                    facc[cs][t] = __builtin_amdgcn_mfma_f32_16x16x32_bf16(va, pb[t], facc[cs][t], 0, 0, 0);
            }
        }
    }

    __syncthreads();  // psT fully consumed; mlp struct may alias

    float s1 = 0.f, s2v = 0.f;
    for (int half = 0; half < 2; ++half) {
        // O half-tile -> oT[m-local 32][c 256]
        for (int cs = 0; cs < 2; ++cs)
            for (int tt = 0; tt < 2; ++tt) {
                const f32x4 fa = facc[cs][2 * half + tt];
                ushort4 pk;
                pk.x = f2bf(fa.x); pk.y = f2bf(fa.y);
                pk.z = f2bf(fa.z); pk.w = f2bf(fa.w);
                *(ushort4*)&sm.mlp.oT[16 * tt + lm][32 * w + 16 * cs + 4 * qd] = pk;
            }
        __syncthreads();

        // MLP phase 1: h = relu(W1 @ O + b1); wave w -> j rows 32w..32w+31
        f32x4 a1[2][2];
        for (int js = 0; js < 2; ++js)
            for (int tt = 0; tt < 2; ++tt) a1[js][tt] = (f32x4){0.f, 0.f, 0.f, 0.f};
        for (int kk = 0; kk < 8; ++kk) {
            bf16x8 bf[2];
            for (int tt = 0; tt < 2; ++tt)
                bf[tt] = *(const bf16x8*)&sm.mlp.oT[16 * tt + lm][32 * kk + 8 * qd];
            for (int js = 0; js < 2; ++js) {
                bf16x8 a = *(const bf16x8*)(W1B + (size_t)(32 * w + 16 * js + lm) * CH + 32 * kk + 8 * qd);
                for (int tt = 0; tt < 2; ++tt)
                    a1[js][tt] = __builtin_amdgcn_mfma_f32_16x16x32_bf16(a, bf[tt], a1[js][tt], 0, 0, 0);
            }
        }
        for (int js = 0; js < 2; ++js) {
            int j0 = 32 * w + 16 * js + 4 * qd;
            float4 bb = *(const float4*)&b1[j0];
            for (int tt = 0; tt < 2; ++tt) {
                ushort4 pk;
                pk.x = f2bf(fmaxf(a1[js][tt].x + bb.x, 0.f));
                pk.y = f2bf(fmaxf(a1[js][tt].y + bb.y, 0.f));
                pk.z = f2bf(fmaxf(a1[js][tt].z + bb.z, 0.f));
                pk.w = f2bf(fmaxf(a1[js][tt].w + bb.w, 0.f));
                *(ushort4*)&sm.mlp.hT[16 * tt + lm][j0] = pk;
            }
        }
        __syncthreads();

        // MLP phase 2: y = W2 @ h + b2; wave w -> c rows 32w..32w+31
        f32x4 a2[2][2];
        for (int cs = 0; cs < 2; ++cs)
            for (int tt = 0; tt < 2; ++tt) a2[cs][tt] = (f32x4){0.f, 0.f, 0.f, 0.f};
        for (int kk = 0; kk < 8; ++kk) {
            bf16x8 hb[2];
            for (int tt = 0; tt < 2; ++tt)
                hb[tt] = *(const bf16x8*)&sm.mlp.hT[16 * tt + lm][32 * kk + 8 * qd];
            for (int cs = 0; cs < 2; ++cs) {
                bf16x8 a = *(const bf16x8*)(W2B + (size_t)(32 * w + 16 * cs + lm) * CH + 32 * kk + 8 * qd);
                for (int tt = 0; tt < 2; ++tt)
                    a2[cs][tt] = __builtin_amdgcn_mfma_f32_16x16x32_bf16(a, hb[tt], a2[cs][tt], 0, 0, 0);
            }
        }
        for (int cs = 0; cs < 2; ++cs) {
            int c0 = 32 * w + 16 * cs + 4 * qd;
            float4 bb = *(const float4*)&b2[c0];
            unsigned short* ybb = yB + ((size_t)b * CH + c0) * NN + m0;
            for (int tt = 0; tt < 2; ++tt) {
                int m = 32 * half + 16 * tt + lm;
                float v0 = a2[cs][tt].x + bb.x, v1 = a2[cs][tt].y + bb.y;
                float v2 = a2[cs][tt].z + bb.z, v3 = a2[cs][tt].w + bb.w;
                s1 += v0 + v1 + v2 + v3;
                s2v += v0 * v0 + v1 * v1 + v2 * v2 + v3 * v3;
                ybb[0 * NN + m] = f2bf(v0);
                ybb[1 * NN + m] = f2bf(v1);
                ybb[2 * NN + m] = f2bf(v2);
                ybb[3 * NN + m] = f2bf(v3);
            }
        }
        if (half == 0) __syncthreads();
    }

    for (int off = 32; off > 0; off >>= 1) {
        s1  += __shfl_down(s1, off, 64);
        s2v += __shfl_down(s2v, off, 64);
    }
    if (lane == 0) { rs1[w] = s1; rs2[w] = s2v; }
    __syncthreads();
    if (tid == 0) {
        float t1 = 0.f, t2 = 0.f;
        for (int i = 0; i < 8; ++i) { t1 += rs1[i]; t2 += rs2[i]; }
        atomicAdd(&sums[b], t1);
        atomicAdd(&sums[BN + b], t2);
    }
}

// ---------------------------------------------------------------------------
// K5: LayerNorm scale from bf16 y
// ---------------------------------------------------------------------------
__global__ __launch_bounds__(256) void ln_final(
    const unsigned short* __restrict__ yB, const float* __restrict__ sums,
    const float* __restrict__ gamma, const float* __restrict__ beta,
    float* __restrict__ out)
{
    const size_t i8 = ((size_t)blockIdx.x * 256 + threadIdx.x) * 8;
    const int b = (int)(i8 >> 20);
    const size_t r = i8 & ((size_t)CH * NN - 1);
    const float inv_n = 1.0f / ((float)CH * (float)NN);
    float mu = sums[b] * inv_n;
    float var = sums[BN + b] * inv_n - mu * mu;
    float inv = rsqrtf(var + LN_EPS);
    uint4 u = *(const uint4*)(yB + i8);
    float y[8];
    y[0] = bf2f(u.x & 0xFFFFu); y[1] = bf2f(u.x >> 16);
    y[2] = bf2f(u.y & 0xFFFFu); y[3] = bf2f(u.y >> 16);
    y[4] = bf2f(u.z & 0xFFFFu); y[5] = bf2f(u.z >> 16);
    y[6] = bf2f(u.w & 0xFFFFu); y[7] = bf2f(u.w >> 16);
    float4 g0 = *(const float4*)(gamma + r);
    float4 g1 = *(const float4*)(gamma + r + 4);
    float4 be0 = *(const float4*)(beta + r);
    float4 be1 = *(const float4*)(beta + r + 4);
    float4 o0, o1;
    o0.x = (y[0] - mu) * inv * g0.x + be0.x;
    o0.y = (y[1] - mu) * inv * g0.y + be0.y;
    o0.z = (y[2] - mu) * inv * g0.z + be0.z;
    o0.w = (y[3] - mu) * inv * g0.w + be0.w;
    o1.x = (y[4] - mu) * inv * g1.x + be1.x;
    o1.y = (y[5] - mu) * inv * g1.y + be1.y;
    o1.z = (y[6] - mu) * inv * g1.z + be1.z;
    o1.w = (y[7] - mu) * inv * g1.w + be1.w;
    *(float4*)(out + i8) = o0;
    *(float4*)(out + i8 + 4) = o1;
}

// ---------------------------------------------------------------------------
extern "C" void kernel_launch(void* const* d_in, const int* in_sizes, int n_in,
                              void* d_out, int out_size, void* d_ws, size_t ws_size,
                              hipStream_t stream)
{
    const float* x     = (const float*)d_in[0];
    const float* Wq    = (const float*)d_in[1];
    const float* bq    = (const float*)d_in[2];
    const float* Wk    = (const float*)d_in[3];
    const float* bk    = (const float*)d_in[4];
    const float* Wv    = (const float*)d_in[5];
    const float* bv    = (const float*)d_in[6];
    const float* W1    = (const float*)d_in[7];
    const float* b1    = (const float*)d_in[8];
    const float* W2    = (const float*)d_in[9];
    const float* b2    = (const float*)d_in[10];
    const float* gamma = (const float*)d_in[11];
    const float* beta  = (const float*)d_in[12];
    float* out = (float*)d_out;

    // workspace layout (~37 MB)
    unsigned short* qB  = (unsigned short*)d_ws;                   // 2 MB
    unsigned short* kTb = qB  + (size_t)BN * NN * QKD;             // 2 MB
    unsigned short* vB  = kTb + (size_t)BN * NN * QKD;             // 16 MB
    unsigned short* yB  = vB  + (size_t)BN * CH * NN;              // 16 MB
    unsigned short* WB  = yB  + (size_t)BN * CH * NN;              // 416 KB
    float* rD   = (float*)(WB + 212992);                           // 128 KB
    float* sums = rD + (size_t)BN * NN;                            // 64 B

    hipMemsetAsync(sums, 0, 2 * BN * sizeof(float), stream);

    conv_weights<<<dim3(64, 5), 256, 0, stream>>>(Wq, Wk, Wv, W1, W2, WB);
    qkv_fused<<<dim3(NN / 64, BN), 256, 0, stream>>>(x, WB, bq, bk, bv,
                                                     qB, kTb, vB);
    colstats<<<dim3(NN / 128, BN), 256, 0, stream>>>(qB, kTb, rD);
    attn_mlp<<<dim3(NN / 64, BN), 512, 0, stream>>>(qB, kTb, vB, rD,
                                                    WB + 81920, b1,
                                                    WB + 147456, b2, yB, sums);
    ln_final<<<dim3((BN * CH * NN) / 2048), 256, 0, stream>>>(yB, sums, gamma,
                                                              beta, out);
}